// Round 19
// baseline (1133.707 us; speedup 1.0000x reference)
//
#include <hip/hip_runtime.h>
#include <hip/hip_fp16.h>

// MemoryAsContextTitan: B=4, S=3968, D=512, H=8, HD=64, CHUNK=496, NPM=32, MEM=1024, nch=8
// R19 = R18 + flash_mha double-buffered K/V LDS: writeKV targets the other buffer so
// ONE barrier per kt suffices (was 2). QBLK=128, 8 waves, grid 256, LDS 106.5 KB.

typedef __attribute__((ext_vector_type(8))) short short8;
typedef __attribute__((ext_vector_type(4))) float f32x4;

static __device__ __forceinline__ unsigned short f32_bf16(float f) {
  unsigned int u = __float_as_uint(f);
  u += 0x7FFFu + ((u >> 16) & 1u);            // RNE
  return (unsigned short)(u >> 16);
}
static __device__ __forceinline__ float bf_f32(unsigned short h) {
  return __uint_as_float(((unsigned)h) << 16);
}
static __device__ __forceinline__ unsigned pk(float lo, float hi) {
  return (unsigned)f32_bf16(lo) | ((unsigned)f32_bf16(hi) << 16);
}

// ---------------------------------------------------------------------------
// GEMM: C[z][m][n] = scale * sum_k A[z][m][k] * Bt[z][n][k]  (+ bias[n])
// (unchanged from R17/R18; see CTY/ASPL/SWZN docs there)
// ---------------------------------------------------------------------------
template<int BM, int BN, int ATY, int BTY, int CTY, bool GUARD, bool BIAS, bool ASPL, int SWZN>
__global__ __launch_bounds__(256) void gemm2(
    const void* __restrict__ Ap, long long Asb, long long Ash, int Ars,
    const void* __restrict__ Bp, long long Bsb, long long Bsh, int Brs,
    void* __restrict__ Cp, long long Csb, long long Csh, int Crs,
    void* __restrict__ Cp2, int csplit, void* __restrict__ Cp3,
    const void* __restrict__ Ap2, long long Asb2,
    const float* __restrict__ bias, float scale, int M, int Kdim, int Hh)
{
  constexpr int LDP = 72;                       // 64 + 8 pad
  constexpr int WN = (BN >= 128) ? 2 : (BM >= 128 ? 1 : 2);
  constexpr int WM = 4 / WN;
  constexpr int MI = BM / (WM * 16);
  constexpr int NI = BN / (WN * 16);
  constexpr int AP = BM / 32;
  constexpr int BP = BN / 32;

  __shared__ unsigned short As[2][BM][LDP];
  __shared__ unsigned short Bs[2][BN][LDP];

  const int tid  = threadIdx.x;
  const int lane = tid & 63;
  const int w    = tid >> 6;
  const int wm   = w / WN, wn = w % WN;
  const int z    = blockIdx.z;
  const int zb   = z / Hh, zh = z - zb * Hh;
  int bx, by;
  if constexpr (SWZN > 0) {
    const int f2 = blockIdx.x;
    const int j2 = f2 >> 3;
    bx = (f2 & 7) + 8 * (j2 / SWZN);
    by = j2 % SWZN;
  } else { bx = blockIdx.x; by = blockIdx.y; }
  const int m0   = bx * BM;
  const int n0   = by * BN;
  const int lrow = lane & 15;
  const int lkB  = (lane >> 4) * 8;
  const int srow = tid >> 3;                    // 0..31
  const int scol = (tid & 7) * 8;               // 0..56

  const float*          Af  = (const float*)Ap          + zb * Asb + zh * Ash;
  const unsigned short* Ahp = (const unsigned short*)Ap + zb * Asb + zh * Ash;
  const unsigned short* A2h = (const unsigned short*)Ap2 + zb * Asb2;
  const float*          Bf  = (const float*)Bp          + zb * Bsb + zh * Bsh;
  const unsigned short* Bhp = (const unsigned short*)Bp + zb * Bsb + zh * Bsh;

  float4 afl[AP][2]; uint4 ahl[AP];
  float4 bfl[BP][2]; uint4 bhl[BP];

  auto loadT = [&](int k0) {
    #pragma unroll
    for (int p = 0; p < AP; ++p) {
      const int row = srow + p * 32;
      const int grow = m0 + row;
      const bool ok = !GUARD || grow < M;
      if constexpr (ATY == 0) {
        if (ok) {
          const float* s = Af + (long long)grow * Ars + k0 + scol;
          afl[p][0] = *(const float4*)s;
          afl[p][1] = *(const float4*)(s + 4);
        } else {
          afl[p][0] = make_float4(0.f,0.f,0.f,0.f);
          afl[p][1] = make_float4(0.f,0.f,0.f,0.f);
        }
      } else {
        if (ok) {
          const unsigned short* src;
          if (!ASPL || grow < 496) src = Ahp + (long long)grow * Ars;
          else                     src = A2h + (long long)(grow - 496) * 512;
          ahl[p] = *(const uint4*)(src + k0 + scol);
        } else ahl[p] = make_uint4(0u,0u,0u,0u);
      }
    }
    #pragma unroll
    for (int p = 0; p < BP; ++p) {
      const int row = srow + p * 32;
      if constexpr (BTY == 0) {
        const float* s = Bf + (long long)(n0 + row) * Brs + k0 + scol;
        bfl[p][0] = *(const float4*)s;
        bfl[p][1] = *(const float4*)(s + 4);
      } else {
        bhl[p] = *(const uint4*)(Bhp + (long long)(n0 + row) * Brs + k0 + scol);
      }
    }
  };
  auto writeT = [&](int buf) {
    #pragma unroll
    for (int p = 0; p < AP; ++p) {
      const int row = srow + p * 32;
      uint4 u;
      if constexpr (ATY == 0) {
        u.x = pk(afl[p][0].x, afl[p][0].y); u.y = pk(afl[p][0].z, afl[p][0].w);
        u.z = pk(afl[p][1].x, afl[p][1].y); u.w = pk(afl[p][1].z, afl[p][1].w);
      } else u = ahl[p];
      *(uint4*)(&As[buf][row][scol]) = u;
    }
    #pragma unroll
    for (int p = 0; p < BP; ++p) {
      const int row = srow + p * 32;
      uint4 u;
      if constexpr (BTY == 0) {
        u.x = pk(bfl[p][0].x, bfl[p][0].y); u.y = pk(bfl[p][0].z, bfl[p][0].w);
        u.z = pk(bfl[p][1].x, bfl[p][1].y); u.w = pk(bfl[p][1].z, bfl[p][1].w);
      } else u = bhl[p];
      *(uint4*)(&Bs[buf][row][scol]) = u;
    }
  };

  f32x4 acc[MI][NI] = {};

  loadT(0);
  writeT(0);
  __syncthreads();

  const int NT = Kdim >> 6;
  int cur = 0;
  for (int t = 0; t < NT; ++t) {
    const bool more = (t + 1) < NT;
    if (more) loadT((t + 1) << 6);

    short8 a8[MI][2], b8[NI][2];
    #pragma unroll
    for (int mi = 0; mi < MI; ++mi) {
      const unsigned short* r = &As[cur][wm * (MI * 16) + mi * 16 + lrow][lkB];
      a8[mi][0] = *(const short8*)r;
      a8[mi][1] = *(const short8*)(r + 32);
    }
    #pragma unroll
    for (int ni = 0; ni < NI; ++ni) {
      const unsigned short* r = &Bs[cur][wn * (NI * 16) + ni * 16 + lrow][lkB];
      b8[ni][0] = *(const short8*)r;
      b8[ni][1] = *(const short8*)(r + 32);
    }
    #pragma unroll
    for (int kk = 0; kk < 2; ++kk)
      #pragma unroll
      for (int mi = 0; mi < MI; ++mi)
        #pragma unroll
        for (int ni = 0; ni < NI; ++ni)
          acc[mi][ni] = __builtin_amdgcn_mfma_f32_16x16x32_bf16(a8[mi][kk], b8[ni][kk], acc[mi][ni], 0, 0, 0);

    if (more) writeT(cur ^ 1);
    __syncthreads();
    cur ^= 1;
  }

  // ---- epilogue ----
  float*          Cf  = (float*)Cp          + zb * Csb + zh * Csh;
  unsigned short* Chn = (unsigned short*)Cp + zb * Csb + zh * Csh;
  unsigned short* Ch2 = (unsigned short*)Cp2;
  unsigned short* Kb3 = (unsigned short*)Cp3;
  const bool trside = (CTY == 4 || CTY == 5) ? (n0 >= csplit) : false;

  #pragma unroll
  for (int ni = 0; ni < NI; ++ni) {
    const int col = n0 + wn * (NI * 16) + ni * 16 + lrow;
    const float bv = BIAS ? bias[col] : 0.0f;
    #pragma unroll
    for (int mi = 0; mi < MI; ++mi) {
      const int rbase = m0 + wm * (MI * 16) + mi * 16 + ((lane >> 4) << 2);
      if constexpr (CTY == 5) {
        ushort4 vt;
        #pragma unroll
        for (int r = 0; r < 4; ++r) {
          const int row = rbase + r;
          const float proj = acc[mi][ni][r] * scale + bv;
          const long long midx = (long long)row * Crs + col;
          const float v = 0.9f * Cf[midx] + 0.1f * proj;
          Cf[midx] = v;
          if (!trside) Kb3[(long long)row * 512 + col] = f32_bf16(v);
          else ((unsigned short*)&vt)[r] = f32_bf16(v);
        }
        if (trside)
          *(ushort4*)(&Ch2[(long long)(rbase >> 10) * 524288
                           + (long long)(col - csplit) * 1024 + (rbase & 1023)]) = vt;
      } else if constexpr (CTY == 8) {
        float* ATTo = (float*)Cp2;
        #pragma unroll
        for (int r = 0; r < 4; ++r) {
          const int row = rbase + r;
          if (row < M) {
            const float v = acc[mi][ni][r] * scale + bv;
            if (col < csplit)
              Kb3[((long long)zb * 496 + row) * 512 + col] = f32_bf16(v);
            else
              ATTo[((long long)zb * 496 + row) * 512 + (col - csplit)] = v;
          }
        }
      } else if constexpr (CTY == 9) {
        const float* ATTp = (const float*)Cp2;
        float* Of = (float*)Cp;
        #pragma unroll
        for (int r = 0; r < 4; ++r) {
          const int row = rbase + r;
          if (row < 496) {
            const float v = acc[mi][ni][r] * scale;
            const float a = ATTp[((long long)zb * 496 + row) * 512 + col];
            Of[((long long)zb * 3968 + (long long)csplit * 496 + row) * 512 + col] = v * a;
          } else if (row < M) {
            Kb3[(long long)zb * 524288 + (long long)(32 + row - 496) * 512 + col]
              = f32_bf16(acc[mi][ni][r] * scale);
          }
        }
      } else if (trside) {
        ushort4 v;
        v.x = f32_bf16(acc[mi][ni][0] * scale + bv);
        v.y = f32_bf16(acc[mi][ni][1] * scale + bv);
        v.z = f32_bf16(acc[mi][ni][2] * scale + bv);
        v.w = f32_bf16(acc[mi][ni][3] * scale + bv);
        *(ushort4*)(&Ch2[(long long)(rbase >> 10) * 524288
                         + (long long)(col - csplit) * 1024 + (rbase & 1023)]) = v;
      } else {
        #pragma unroll
        for (int r = 0; r < 4; ++r) {
          const int row = rbase + r;
          if (!GUARD || row < M) {
            const float v = acc[mi][ni][r] * scale + bv;
            if constexpr (CTY == 0)      Cf [(long long)row * Crs + col] = v;
            else                         Chn[(long long)row * Crs + col] = f32_bf16(v);
          }
        }
      }
    }
  }
}

// ---------------------------------------------------------------------------
// Flash MHA, QBLK=128 / 8 waves / 512 threads / double-buffered K/V LDS.
// Grid 256: f -> xcd=f&7, j=f>>3, bh=xcd+8*(j>>3), qt=j&7.
// One barrier per kt: writeKV targets the other buffer (no reader), and the
// barrier orders this iter's reads of buf[cur] before next iter's overwrite.
// Per-wave inner math identical to R7/R15/R18. LDS 106.5 KB.
// ---------------------------------------------------------------------------
__global__ __launch_bounds__(512) void flash_mha(
    const unsigned short* __restrict__ QK, const unsigned short* __restrict__ Vt,
    unsigned short* __restrict__ OH)
{
  __shared__ unsigned short Ks[2][128][72];   // 36.9KB ([0] reused as Os[128][72])
  __shared__ unsigned short Vs[2][64][136];   // 34.8KB
  __shared__ unsigned short Ps[128][136];     // 34.8KB, per-wave 16-row slabs

  const int tid = threadIdx.x, lane = tid & 63, w = tid >> 6;   // w 0..7
  const int f = blockIdx.x;                 // 256 blocks
  const int xcd = f & 7, j = f >> 3;        // j 0..31
  const int bh = xcd + 8 * (j >> 3);        // 0..31, 4 bh per XCD
  const int qt = j & 7;                     // 0..7
  const int b = bh >> 3, h = bh & 7;
  const int q0 = qt * 128;
  const unsigned short* Qp = QK + (long long)b * 1048576 + h * 64;
  const unsigned short* Kp = Qp + 512;
  const unsigned short* Vp = Vt + (long long)b * 524288 + (long long)(h * 64) * 1024;
  unsigned short* Op = OH + (long long)b * 524288 + h * 64;

  const int lr = lane & 15, g = lane >> 4, lk = g * 8;
  const int wq = w * 16;                    // 0..112

  short8 qb[2];
  qb[0] = *(const short8*)(Qp + (long long)(q0 + wq + lr) * 1024 + lk);
  qb[1] = *(const short8*)(Qp + (long long)(q0 + wq + lr) * 1024 + 32 + lk);

  // staging with 512 threads: K 128x64 (4 thr/row, 2 uint4), V 64x128 (8 thr/row, 2 uint4)
  const int krow = tid >> 2, kcol = (tid & 3) * 16;
  const int vrow = tid >> 3, vcol = (tid & 7) * 16;

  uint4 kl[2], vl[2];
  auto loadKV = [&](int kt) {
    kl[0] = *(const uint4*)(Kp + (long long)(kt * 128 + krow) * 1024 + kcol);
    kl[1] = *(const uint4*)(Kp + (long long)(kt * 128 + krow) * 1024 + kcol + 8);
    vl[0] = *(const uint4*)(Vp + (long long)vrow * 1024 + kt * 128 + vcol);
    vl[1] = *(const uint4*)(Vp + (long long)vrow * 1024 + kt * 128 + vcol + 8);
  };
  auto writeKV = [&](int buf) {
    *(uint4*)(&Ks[buf][krow][kcol])     = kl[0];
    *(uint4*)(&Ks[buf][krow][kcol + 8]) = kl[1];
    *(uint4*)(&Vs[buf][vrow][vcol])     = vl[0];
    *(uint4*)(&Vs[buf][vrow][vcol + 8]) = vl[1];
  };

  loadKV(0); writeKV(0);
  __syncthreads();

  f32x4 acc[4] = {};                        // O^T: acc[nd][r] = O[d=16nd+4g+r][q=wq+lr]
  float m = -1e30f, l = 0.f;                // per-lane scalars (q = wq+lr)

  int cur = 0;
  for (int kt = 0; kt < 8; ++kt) {
    const bool more = kt < 7;
    if (more) loadKV(kt + 1);               // prefetch next K/V tile into registers

    // ---- S = K·Q^T : s[ni][r] = score[k=16ni+4g+r][q=wq+lr] ----
    f32x4 s[8] = {};
    #pragma unroll
    for (int ks = 0; ks < 2; ++ks)
      #pragma unroll
      for (int ni = 0; ni < 8; ++ni) {
        const short8 ka = *(const short8*)(&Ks[cur][ni * 16 + lr][ks * 32 + lk]);
        s[ni] = __builtin_amdgcn_mfma_f32_16x16x32_bf16(ka, qb[ks], s[ni], 0, 0, 0);
      }

    // ---- per-lane scalar online softmax ----
    float rm = -1e30f;
    #pragma unroll
    for (int ni = 0; ni < 8; ++ni)
      #pragma unroll
      for (int r = 0; r < 4; ++r) { s[ni][r] *= 0.125f; rm = fmaxf(rm, s[ni][r]); }
    rm = fmaxf(rm, __shfl_xor(rm, 16));
    rm = fmaxf(rm, __shfl_xor(rm, 32));

    const float mn = fmaxf(m, rm);
    const float al = __expf(m - mn);
    m = mn;
    float ls = 0.f;
    #pragma unroll
    for (int ni = 0; ni < 8; ++ni)
      #pragma unroll
      for (int r = 0; r < 4; ++r) { s[ni][r] = __expf(s[ni][r] - m); ls += s[ni][r]; }
    ls += __shfl_xor(ls, 16);
    ls += __shfl_xor(ls, 32);
    l = l * al + ls;
    #pragma unroll
    for (int nd = 0; nd < 4; ++nd)
      #pragma unroll
      for (int r = 0; r < 4; ++r) acc[nd][r] *= al;

    // ---- P -> per-wave LDS slab: Ps[q=wq+lr][k=16ni+4g+r] ----
    #pragma unroll
    for (int ni = 0; ni < 8; ++ni)
      #pragma unroll
      for (int r = 0; r < 4; ++r)
        Ps[wq + lr][ni * 16 + (g << 2) + r] = f32_bf16(s[ni][r]);

    // ---- O^T += V·P^T ----
    #pragma unroll
    for (int ks2 = 0; ks2 < 4; ++ks2) {
      const short8 pb = *(const short8*)(&Ps[wq + lr][ks2 * 32 + lk]);
      #pragma unroll
      for (int nd = 0; nd < 4; ++nd) {
        const short8 va = *(const short8*)(&Vs[cur][nd * 16 + lr][ks2 * 32 + lk]);
        acc[nd] = __builtin_amdgcn_mfma_f32_16x16x32_bf16(va, pb, acc[nd], 0, 0, 0);
      }
    }

    if (more) writeKV(cur ^ 1);             // other buffer: no reader conflict
    __syncthreads();                        // orders reads-of-cur before next overwrite
    cur ^= 1;
  }

  // ---- O^T -> Os (aliased on Ks[0]) -> coalesced OH write ----
  unsigned short (*Os)[72] = (unsigned short (*)[72])&Ks[0][0][0];
  const float inv = 1.0f / l;
  #pragma unroll
  for (int nd = 0; nd < 4; ++nd)
    #pragma unroll
    for (int r = 0; r < 4; ++r)
      Os[wq + lr][nd * 16 + (g << 2) + r] = f32_bf16(acc[nd][r] * inv);
  __syncthreads();
  const int orow = tid >> 2, ocol = (tid & 3) * 16;   // 128 rows x 4 thr/row
  const uint4 u0 = *(const uint4*)(&Os[orow][ocol]);
  const uint4 u1 = *(const uint4*)(&Os[orow][ocol + 8]);
  *(uint4*)(Op + (long long)(q0 + orow) * 512 + ocol) = u0;
  *(uint4*)(Op + (long long)(q0 + orow) * 512 + ocol + 8) = u1;
}

// ---------------------------------------------------------------------------
struct TP7 { const float* s[7]; unsigned short* d[7]; };
__global__ __launch_bounds__(256) void transpose7(TP7 tp)
{
  __shared__ float tile[32][33];
  const float* in = tp.s[blockIdx.z];
  unsigned short* out = tp.d[blockIdx.z];
  const int c0 = blockIdx.x * 32, r0 = blockIdx.y * 32;
  const int xx = threadIdx.x & 31, ys = threadIdx.x >> 5;
  #pragma unroll
  for (int yy = ys; yy < 32; yy += 8)
    tile[yy][xx] = in[(long long)(r0 + yy) * 512 + c0 + xx];
  __syncthreads();
  #pragma unroll
  for (int yy = ys; yy < 32; yy += 8)
    out[(long long)(c0 + yy) * 512 + r0 + xx] = f32_bf16(tile[xx][yy]);
}

// ---------------------------------------------------------------------------
// Row softmax, row length 1024, one wave per row. f32 in -> bf16 out (obuf).
// ---------------------------------------------------------------------------
__global__ __launch_bounds__(256) void softmax_rows_bf(
    const float* __restrict__ buf, unsigned short* __restrict__ obuf,
    int rowsPerZ, long long zStride)
{
  const int gr   = blockIdx.x * 4 + (threadIdx.x >> 6);
  const int lane = threadIdx.x & 63;
  const int z = gr / rowsPerZ;
  const int i = gr - z * rowsPerZ;
  const float* pf = buf + (long long)z * zStride + (long long)i * 1024 + lane * 16;
  float v[16];
  #pragma unroll
  for (int j = 0; j < 4; ++j) {
    const float4 f = ((const float4*)pf)[j];
    v[4*j+0] = f.x; v[4*j+1] = f.y; v[4*j+2] = f.z; v[4*j+3] = f.w;
  }
  float mx = v[0];
  #pragma unroll
  for (int j = 1; j < 16; ++j) mx = fmaxf(mx, v[j]);
  #pragma unroll
  for (int d = 32; d; d >>= 1) mx = fmaxf(mx, __shfl_xor(mx, d));
  float s = 0.0f;
  #pragma unroll
  for (int j = 0; j < 16; ++j) { v[j] = __expf(v[j] - mx); s += v[j]; }
  #pragma unroll
  for (int d = 32; d; d >>= 1) s += __shfl_xor(s, d);
  const float inv = 1.0f / s;
  unsigned short* ph = obuf + (long long)z * zStride + (long long)i * 1024 + lane * 16;
  unsigned uu[8];
  #pragma unroll
  for (int j = 0; j < 8; ++j) uu[j] = pk(v[2*j] * inv, v[2*j+1] * inv);
  ((uint4*)ph)[0] = make_uint4(uu[0], uu[1], uu[2], uu[3]);
  ((uint4*)ph)[1] = make_uint4(uu[4], uu[5], uu[6], uu[7]);
}

// --------------------------- elementwise helpers ---------------------------
__global__ __launch_bounds__(256) void copy_pm8(const float* __restrict__ pm, unsigned short* __restrict__ comb8)
{
  const int ci = blockIdx.y;
  const int idx = blockIdx.x * 256 + threadIdx.x;   // 8192 per ci
  const int b = idx >> 11, e = idx & 2047;
  const int row = e >> 6, d8 = (e & 63) * 8;
  const float* s = pm + row * 512 + d8;
  const float4 f0 = *(const float4*)s;
  const float4 f1 = *(const float4*)(s + 4);
  uint4 u; u.x = pk(f0.x, f0.y); u.y = pk(f0.z, f0.w); u.z = pk(f1.x, f1.y); u.w = pk(f1.z, f1.w);
  *(uint4*)(comb8 + (long long)ci * 2097152 + (long long)b * 524288 + row * 512 + d8) = u;
}

__global__ __launch_bounds__(256) void copy_chunk8(const float* __restrict__ x, unsigned short* __restrict__ comb8)
{
  const int ci = blockIdx.y;
  const int idx = blockIdx.x * 256 + threadIdx.x;   // 126976 per ci
  const int b = idx / 31744, e = idx % 31744;
  const int row = e >> 6, d8 = (e & 63) * 8;
  const float* s = x + ((long long)b * 3968 + ci * 496 + row) * 512 + d8;
  const float4 f0 = *(const float4*)s;
  const float4 f1 = *(const float4*)(s + 4);
  uint4 u; u.x = pk(f0.x, f0.y); u.y = pk(f0.z, f0.w); u.z = pk(f1.x, f1.y); u.w = pk(f1.z, f1.w);
  *(uint4*)(comb8 + (long long)ci * 2097152 + (long long)b * 524288 + (528 + row) * 512 + d8) = u;
}

__global__ __launch_bounds__(256) void init_kv(const float* __restrict__ mkb, const float* __restrict__ mvb,
                                               float* __restrict__ master, unsigned short* __restrict__ Kb)
{
  const int idx = blockIdx.x * 256 + threadIdx.x;   // 1M : [4096 rows][256 col4]
  const int c4 = (idx & 255) * 4;
  const long long row = idx >> 8;
  const float4 v = *(const float4*)((c4 < 512) ? (mkb + c4) : (mvb + c4 - 512));
  *(float4*)(master + row * 1024 + c4) = v;
  if (c4 < 512) {
    ushort4 h; h.x = f32_bf16(v.x); h.y = f32_bf16(v.y); h.z = f32_bf16(v.z); h.w = f32_bf16(v.w);
    *(ushort4*)(Kb + row * 512 + c4) = h;
  }
}

__global__ __launch_bounds__(256) void init_vt(const float* __restrict__ mvb, unsigned short* __restrict__ VT)
{
  const int idx = blockIdx.x * 256 + threadIdx.x;   // 262144 : [4][512][128 k8]
  const int k8 = (idx & 127) * 8;
  const int d  = (idx >> 7) & 511;
  const int b  = idx >> 16;
  const unsigned short hv = f32_bf16(mvb[d]);
  const ushort4 h4 = make_ushort4(hv, hv, hv, hv);
  unsigned short* dst = VT + (long long)b * 524288 + (long long)d * 1024 + k8;
  *(ushort4*)dst = h4; *(ushort4*)(dst + 4) = h4;
}

__global__ __launch_bounds__(256) void fuse_bias(const float* __restrict__ bq, const float* __restrict__ mq,
                                                 const float* __restrict__ mqb, float* __restrict__ bqm)
{
  const int c = blockIdx.x * 256 + threadIdx.x;     // 512
  float s = mqb[c];
  for (int j = 0; j < 512; ++j) s += bq[j] * mq[j * 512 + c];
  bqm[c] = s;
}

__global__ __launch_bounds__(256) void fuse_bias2(const float* __restrict__ aob,
                                                  const float* __restrict__ mkw, const float* __restrict__ mkb,
                                                  const float* __restrict__ mvw, const float* __restrict__ mvb,
                                                  float* __restrict__ baokv)
{
  const int c = blockIdx.x * 256 + threadIdx.x;     // 1024
  const float* w  = (c < 512) ? mkw : mvw;
  const float* bb = (c < 512) ? mkb : mvb;
  const int cc = c & 511;
  float s = bb[cc];
  for (int j = 0; j < 512; ++j) s += aob[j] * w[j * 512 + cc];
  baokv[c] = s;
}

// ---------------------------------------------------------------------------
extern "C" void kernel_launch(void* const* d_in, const int* in_sizes, int n_in,
                              void* d_out, int out_size, void* d_ws, size_t ws_size,
                              hipStream_t stream)
{
  (void)in_sizes; (void)n_in; (void)out_size; (void)ws_size;
  const float* x   = (const float*)d_in[0];
  const float* pm  = (const float*)d_in[1];
  const float* Wq  = (const float*)d_in[2];
  const float* bq  = (const float*)d_in[3];
  const float* mkw = (const float*)d_in[4];
  const float* mkb = (const float*)d_in[5];
  const float* mvw = (const float*)d_in[6];
  const float* mvb = (const float*)d_in[7];
  const float* mqw = (const float*)d_in[8];
  const float* mqb = (const float*)d_in[9];
  const float* aqw = (const float*)d_in[10];
  const float* aqb = (const float*)d_in[11];
  const float* akw = (const float*)d_in[12];
  const float* akb = (const float*)d_in[13];
  const float* avw = (const float*)d_in[14];
  const float* avb = (const float*)d_in[15];
  const float* aow = (const float*)d_in[16];
  const float* aob = (const float*)d_in[17];
  float* out = (float*)d_out;

  char* wsp = (char*)d_ws;
  size_t off = 0;
  auto alloc = [&](size_t b) -> void* { void* p = wsp + off; off += (b + 255) & ~(size_t)255; return p; };

  unsigned short* WTmq  = (unsigned short*)alloc(524288);   // mq^T bf16 [512][512]
  unsigned short* WKV   = (unsigned short*)alloc(1048576);  // [mk;mv]^T [1024][512]
  unsigned short* WQKV  = (unsigned short*)alloc(1572864);  // [aq;ak;av]^T [1536][512]
  unsigned short* Wqm   = (unsigned short*)alloc(524288);   // (Wq@mq)^T bf16
  unsigned short* WaoKV = (unsigned short*)alloc(1048576);  // (Wao@[mk|mv])^T bf16 [1024][512]
  unsigned short* WQA   = (unsigned short*)alloc(1048576);  // [(Wao@mq)^T ; ao^T] [1024][512]
  float* bqkv  = (float*)alloc(6144);
  float* bqm   = (float*)alloc(2048);
  float* baokv = (float*)alloc(4096);
  float* bqa   = (float*)alloc(4096);                       // [baomq | aob]
  float*          master = (float*)alloc(16777216);        // f32 [4,1024,1024] EMA'd [K|V]
  unsigned short* Kb   = (unsigned short*)alloc(4194304);  // bf16 [4,1024,512]
  unsigned short* VT   = (unsigned short*)alloc(4194304);  // bf16 [4,512,1024] (retrieve V^T)
  unsigned short* VTm  = (unsigned short*)alloc(4194304);  // bf16 [4,512,1024] (MHA V^T)
  unsigned short* QP1  = (unsigned short*)alloc(16252928); // bf16 [4,3968,512]
  unsigned short* QP   = (unsigned short*)alloc(2031616);  // bf16 [4,496,512] (qp2)
  unsigned short* comb8= (unsigned short*)alloc(33554432); // bf16 [8][4,1024,512]
  unsigned short* QKb  = (unsigned short*)alloc(8388608);  // bf16 [4,1024,1024] (q|k)
  unsigned short* OH   = (unsigned short*)alloc(4194304);  // bf16 [4,1024,512]
  float*          ATT  = (float*)alloc(4063232);           // f32 [4,496,512]
  float*          SC   = (float*)alloc(16515072);          // f32 [4,992,1024]
  unsigned short* SCb  = (unsigned short*)alloc(8257536);  // bf16 [4,992,1024]

  const long long XBS = 2031616, BS = 524288, QBS = 253952;
  const long long SCB2 = 1015808;               // 992*1024
  const float sr = 0.044194173824159216f;       // 1/sqrt(512)

  // -------- prep (once per call) --------
  TP7 tp;
  tp.s[0] = mqw; tp.d[0] = WTmq;
  tp.s[1] = mkw; tp.d[1] = WKV;
  tp.s[2] = mvw; tp.d[2] = WKV + 262144;
  tp.s[3] = aqw; tp.d[3] = WQKV;
  tp.s[4] = akw; tp.d[4] = WQKV + 262144;
  tp.s[5] = avw; tp.d[5] = WQKV + 524288;
  tp.s[6] = aow; tp.d[6] = WQA + 262144;        // ao^T -> second half of WQA
  transpose7<<<dim3(16,16,7),256,0,stream>>>(tp);
  gemm2<64,64,1,0,2,false,false,false,0><<<dim3(8,8,1),256,0,stream>>>(
    WTmq, 0, 0, 512, Wq, 0, 0, 512, Wqm, 0, 0, 512,
    nullptr, 0, nullptr, nullptr, 0, nullptr, 1.0f, 512, 512, 1);
  gemm2<64,64,1,0,2,false,false,false,0><<<dim3(16,8,1),256,0,stream>>>(
    WKV, 0, 0, 512, aow, 0, 0, 512, WaoKV, 0, 0, 512,
    nullptr, 0, nullptr, nullptr, 0, nullptr, 1.0f, 1024, 512, 1);
  gemm2<64,64,1,0,2,false,false,false,0><<<dim3(8,8,1),256,0,stream>>>(
    WTmq, 0, 0, 512, aow, 0, 0, 512, WQA, 0, 0, 512,
    nullptr, 0, nullptr, nullptr, 0, nullptr, 1.0f, 512, 512, 1);
  fuse_bias<<<2,256,0,stream>>>(bq, mqw, mqb, bqm);
  fuse_bias<<<2,256,0,stream>>>(aob, mqw, mqb, bqa);
  fuse_bias2<<<4,256,0,stream>>>(aob, mkw, mkb, mvw, mvb, baokv);
  hipMemcpyAsync(bqa + 512, aob, 2048, hipMemcpyDeviceToDevice, stream);
  // qp1 for ALL chunks: QP1 = bf16(x @ Wqm + bqm), M = 15872
  gemm2<128,64,0,1,2,false,true,false,0><<<dim3(124,8,1),256,0,stream>>>(
    x, 0, 0, 512, Wqm, 0, 0, 512,
    QP1, 0, 0, 512, nullptr, 0, nullptr, nullptr, 0, bqm, 1.0f, 15872, 512, 1);
  hipMemcpyAsync(bqkv,       aqb, 2048, hipMemcpyDeviceToDevice, stream);
  hipMemcpyAsync(bqkv + 512, akb, 2048, hipMemcpyDeviceToDevice, stream);
  hipMemcpyAsync(bqkv +1024, avb, 2048, hipMemcpyDeviceToDevice, stream);
  init_kv<<<4096,256,0,stream>>>(mkb, mvb, master, Kb);
  init_vt<<<1024,256,0,stream>>>(mvb, VT);
  copy_pm8<<<dim3(32,8),256,0,stream>>>(pm, comb8);
  copy_chunk8<<<dim3(496,8),256,0,stream>>>(x, comb8);

  // -------- prologue: scores1[0] + softmax + hist[0] (initial KV state) --------
  gemm2<64,64,1,1,0,true,false,false,0><<<dim3(8,16,4),256,0,stream>>>(
    QP1, XBS, 0, 512, Kb, BS, 0, 512,
    SC, SCB2, 0, 1024, nullptr, 0, nullptr, nullptr, 0, nullptr, sr, 496, 512, 1);
  softmax_rows_bf<<<496,256,0,stream>>>(SC, SCb, 496, SCB2);
  gemm2<64,64,1,1,2,true,false,false,0><<<dim3(8,8,4),256,0,stream>>>(
    SCb, SCB2, 0, 1024, VT, BS, 0, 1024,
    comb8 + 32 * 512, BS, 0, 512, nullptr, 0, nullptr, nullptr, 0, nullptr, 1.0f, 496, 1024, 1);

  for (int ci = 0; ci < 8; ++ci) {
    unsigned short* comb = comb8 + (long long)ci * 2097152;
    const bool last = (ci == 7);
    const int Mm = last ? 496 : 992;

    // MHA qkv (XCD-swizzled flat grid 768 = 32 M-stripes x 24 N-blocks)
    gemm2<128,64,1,1,4,false,true,false,24><<<dim3(768,1,1),256,0,stream>>>(
      comb, 0, 0, 512, WQKV, 0, 0, 512,
      QKb, 0, 0, 1024, VTm, 1024, nullptr, nullptr, 0, bqkv, 1.0f, 4096, 512, 1);
    flash_mha<<<256,512,0,stream>>>(QKb, VTm, OH);

    // KV-EMA (XCD-swizzled flat grid 512 = 32 x 16): master = 0.9*master + 0.1*(OH@WaoKV+b)
    gemm2<128,64,1,1,5,false,true,false,16><<<dim3(512,1,1),256,0,stream>>>(
      OH, 0, 0, 512, WaoKV, 0, 0, 512,
      master, 0, 0, 1024, VT, 512, Kb, nullptr, 0, baokv, 1.0f, 4096, 512, 1);
    // qp2 + ATT merged: [QP | ATT] = OH[:,528:] @ [Wao@mq | Wao] + [baomq | aob]
    gemm2<64,64,1,1,8,true,true,false,0><<<dim3(8,16,4),256,0,stream>>>(
      OH + 528 * 512, BS, 0, 512, WQA, 0, 0, 512,
      nullptr, 0, 0, 512, ATT, 512, QP, nullptr, 0, bqa, 1.0f, 496, 512, 1);

    // merged scores: rows 0..495 = qp2[ci], rows 496..991 = qp1[ci+1]
    gemm2<64,64,1,1,0,true,false,true,0><<<dim3(last?8:16,16,4),256,0,stream>>>(
      QP, QBS, 0, 512, Kb, BS, 0, 512,
      SC, SCB2, 0, 1024, nullptr, 0, nullptr,
      QP1 + (long long)(ci + 1) * 253952, XBS, nullptr, sr, Mm, 512, 1);
    softmax_rows_bf<<<(last?496:992),256,0,stream>>>(SC, SCb, Mm, SCB2);
    // merged PV: rows<496 -> out[ci] (outmul with ATT); rows>=496 -> hist[ci+1]
    gemm2<64,64,1,1,9,true,false,false,0><<<dim3(last?8:16,8,4),256,0,stream>>>(
      SCb, SCB2, 0, 1024, VT, BS, 0, 1024,
      out, 0, 0, 512, ATT, ci, last ? nullptr : (comb8 + (long long)(ci + 1) * 2097152),
      nullptr, 0, nullptr, 1.0f, Mm, 1024, 1);
  }
}

// Round 20
// 1097.375 us; speedup vs baseline: 1.0331x; 1.0331x over previous
//
#include <hip/hip_runtime.h>
#include <hip/hip_fp16.h>

// MemoryAsContextTitan: B=4, S=3968, D=512, H=8, HD=64, CHUNK=496, NPM=32, MEM=1024, nch=8
// R20 = exact revert to R18 (best measured: 1098 us). R19's double-buffered K/V cost
// a 2->1 blocks/CU occupancy drop (LDS 70.6->106.5 KB) that outweighed the barrier
// savings. R18: flash QBLK=128, 8 waves, 512 threads, grid 256, single-buffered K/V.

typedef __attribute__((ext_vector_type(8))) short short8;
typedef __attribute__((ext_vector_type(4))) float f32x4;

static __device__ __forceinline__ unsigned short f32_bf16(float f) {
  unsigned int u = __float_as_uint(f);
  u += 0x7FFFu + ((u >> 16) & 1u);            // RNE
  return (unsigned short)(u >> 16);
}
static __device__ __forceinline__ float bf_f32(unsigned short h) {
  return __uint_as_float(((unsigned)h) << 16);
}
static __device__ __forceinline__ unsigned pk(float lo, float hi) {
  return (unsigned)f32_bf16(lo) | ((unsigned)f32_bf16(hi) << 16);
}

// ---------------------------------------------------------------------------
// GEMM: C[z][m][n] = scale * sum_k A[z][m][k] * Bt[z][n][k]  (+ bias[n])
// ATY/BTY: 0 = f32 source (convert to bf16), 1 = bf16 source.
// ASPL: row<496 reads Ap, row>=496 reads Ap2 (bf16, stride 512, batch Asb2).
// SWZN: if >0, grid is flat (x = NX*SWZN); decode bx=(f&7)+8*((f>>3)/SWZN),
//       by=(f>>3)%SWZN -> all SWZN N-blocks of an M-stripe on one XCD.
// CTY: 0 f32, 2 bf16,
//      4 split: col<csplit -> bf16 to Cp; col>=csplit -> bf16 TRANSPOSED to Cp2,
//      5 KV-EMA: master RMW + Kb bf16 / VT transposed,
//      8 qp2+ATT: col<csplit -> bf16 to Cp3 (QP); col>=csplit -> f32 to Cp2 (ATT),
//      9 merged PV: row<496 -> outmul; row>=496 -> bf16 hist to Cp3.
// Double-buffered BK=64, register-prefetch staging. Kdim % 64 == 0.
// ---------------------------------------------------------------------------
template<int BM, int BN, int ATY, int BTY, int CTY, bool GUARD, bool BIAS, bool ASPL, int SWZN>
__global__ __launch_bounds__(256) void gemm2(
    const void* __restrict__ Ap, long long Asb, long long Ash, int Ars,
    const void* __restrict__ Bp, long long Bsb, long long Bsh, int Brs,
    void* __restrict__ Cp, long long Csb, long long Csh, int Crs,
    void* __restrict__ Cp2, int csplit, void* __restrict__ Cp3,
    const void* __restrict__ Ap2, long long Asb2,
    const float* __restrict__ bias, float scale, int M, int Kdim, int Hh)
{
  constexpr int LDP = 72;                       // 64 + 8 pad
  constexpr int WN = (BN >= 128) ? 2 : (BM >= 128 ? 1 : 2);
  constexpr int WM = 4 / WN;
  constexpr int MI = BM / (WM * 16);
  constexpr int NI = BN / (WN * 16);
  constexpr int AP = BM / 32;
  constexpr int BP = BN / 32;

  __shared__ unsigned short As[2][BM][LDP];
  __shared__ unsigned short Bs[2][BN][LDP];

  const int tid  = threadIdx.x;
  const int lane = tid & 63;
  const int w    = tid >> 6;
  const int wm   = w / WN, wn = w % WN;
  const int z    = blockIdx.z;
  const int zb   = z / Hh, zh = z - zb * Hh;
  int bx, by;
  if constexpr (SWZN > 0) {
    const int f2 = blockIdx.x;
    const int j2 = f2 >> 3;
    bx = (f2 & 7) + 8 * (j2 / SWZN);
    by = j2 % SWZN;
  } else { bx = blockIdx.x; by = blockIdx.y; }
  const int m0   = bx * BM;
  const int n0   = by * BN;
  const int lrow = lane & 15;
  const int lkB  = (lane >> 4) * 8;
  const int srow = tid >> 3;                    // 0..31
  const int scol = (tid & 7) * 8;               // 0..56

  const float*          Af  = (const float*)Ap          + zb * Asb + zh * Ash;
  const unsigned short* Ahp = (const unsigned short*)Ap + zb * Asb + zh * Ash;
  const unsigned short* A2h = (const unsigned short*)Ap2 + zb * Asb2;
  const float*          Bf  = (const float*)Bp          + zb * Bsb + zh * Bsh;
  const unsigned short* Bhp = (const unsigned short*)Bp + zb * Bsb + zh * Bsh;

  float4 afl[AP][2]; uint4 ahl[AP];
  float4 bfl[BP][2]; uint4 bhl[BP];

  auto loadT = [&](int k0) {
    #pragma unroll
    for (int p = 0; p < AP; ++p) {
      const int row = srow + p * 32;
      const int grow = m0 + row;
      const bool ok = !GUARD || grow < M;
      if constexpr (ATY == 0) {
        if (ok) {
          const float* s = Af + (long long)grow * Ars + k0 + scol;
          afl[p][0] = *(const float4*)s;
          afl[p][1] = *(const float4*)(s + 4);
        } else {
          afl[p][0] = make_float4(0.f,0.f,0.f,0.f);
          afl[p][1] = make_float4(0.f,0.f,0.f,0.f);
        }
      } else {
        if (ok) {
          const unsigned short* src;
          if (!ASPL || grow < 496) src = Ahp + (long long)grow * Ars;
          else                     src = A2h + (long long)(grow - 496) * 512;
          ahl[p] = *(const uint4*)(src + k0 + scol);
        } else ahl[p] = make_uint4(0u,0u,0u,0u);
      }
    }
    #pragma unroll
    for (int p = 0; p < BP; ++p) {
      const int row = srow + p * 32;
      if constexpr (BTY == 0) {
        const float* s = Bf + (long long)(n0 + row) * Brs + k0 + scol;
        bfl[p][0] = *(const float4*)s;
        bfl[p][1] = *(const float4*)(s + 4);
      } else {
        bhl[p] = *(const uint4*)(Bhp + (long long)(n0 + row) * Brs + k0 + scol);
      }
    }
  };
  auto writeT = [&](int buf) {
    #pragma unroll
    for (int p = 0; p < AP; ++p) {
      const int row = srow + p * 32;
      uint4 u;
      if constexpr (ATY == 0) {
        u.x = pk(afl[p][0].x, afl[p][0].y); u.y = pk(afl[p][0].z, afl[p][0].w);
        u.z = pk(afl[p][1].x, afl[p][1].y); u.w = pk(afl[p][1].z, afl[p][1].w);
      } else u = ahl[p];
      *(uint4*)(&As[buf][row][scol]) = u;
    }
    #pragma unroll
    for (int p = 0; p < BP; ++p) {
      const int row = srow + p * 32;
      uint4 u;
      if constexpr (BTY == 0) {
        u.x = pk(bfl[p][0].x, bfl[p][0].y); u.y = pk(bfl[p][0].z, bfl[p][0].w);
        u.z = pk(bfl[p][1].x, bfl[p][1].y); u.w = pk(bfl[p][1].z, bfl[p][1].w);
      } else u = bhl[p];
      *(uint4*)(&Bs[buf][row][scol]) = u;
    }
  };

  f32x4 acc[MI][NI] = {};

  loadT(0);
  writeT(0);
  __syncthreads();

  const int NT = Kdim >> 6;
  int cur = 0;
  for (int t = 0; t < NT; ++t) {
    const bool more = (t + 1) < NT;
    if (more) loadT((t + 1) << 6);

    short8 a8[MI][2], b8[NI][2];
    #pragma unroll
    for (int mi = 0; mi < MI; ++mi) {
      const unsigned short* r = &As[cur][wm * (MI * 16) + mi * 16 + lrow][lkB];
      a8[mi][0] = *(const short8*)r;
      a8[mi][1] = *(const short8*)(r + 32);
    }
    #pragma unroll
    for (int ni = 0; ni < NI; ++ni) {
      const unsigned short* r = &Bs[cur][wn * (NI * 16) + ni * 16 + lrow][lkB];
      b8[ni][0] = *(const short8*)r;
      b8[ni][1] = *(const short8*)(r + 32);
    }
    #pragma unroll
    for (int kk = 0; kk < 2; ++kk)
      #pragma unroll
      for (int mi = 0; mi < MI; ++mi)
        #pragma unroll
        for (int ni = 0; ni < NI; ++ni)
          acc[mi][ni] = __builtin_amdgcn_mfma_f32_16x16x32_bf16(a8[mi][kk], b8[ni][kk], acc[mi][ni], 0, 0, 0);

    if (more) writeT(cur ^ 1);
    __syncthreads();
    cur ^= 1;
  }

  // ---- epilogue ----
  float*          Cf  = (float*)Cp          + zb * Csb + zh * Csh;
  unsigned short* Chn = (unsigned short*)Cp + zb * Csb + zh * Csh;
  unsigned short* Ch2 = (unsigned short*)Cp2;
  unsigned short* Kb3 = (unsigned short*)Cp3;
  const bool trside = (CTY == 4 || CTY == 5) ? (n0 >= csplit) : false;

  #pragma unroll
  for (int ni = 0; ni < NI; ++ni) {
    const int col = n0 + wn * (NI * 16) + ni * 16 + lrow;
    const float bv = BIAS ? bias[col] : 0.0f;
    #pragma unroll
    for (int mi = 0; mi < MI; ++mi) {
      const int rbase = m0 + wm * (MI * 16) + mi * 16 + ((lane >> 4) << 2);
      if constexpr (CTY == 5) {
        ushort4 vt;
        #pragma unroll
        for (int r = 0; r < 4; ++r) {
          const int row = rbase + r;
          const float proj = acc[mi][ni][r] * scale + bv;
          const long long midx = (long long)row * Crs + col;
          const float v = 0.9f * Cf[midx] + 0.1f * proj;
          Cf[midx] = v;
          if (!trside) Kb3[(long long)row * 512 + col] = f32_bf16(v);
          else ((unsigned short*)&vt)[r] = f32_bf16(v);
        }
        if (trside)
          *(ushort4*)(&Ch2[(long long)(rbase >> 10) * 524288
                           + (long long)(col - csplit) * 1024 + (rbase & 1023)]) = vt;
      } else if constexpr (CTY == 8) {
        float* ATTo = (float*)Cp2;
        #pragma unroll
        for (int r = 0; r < 4; ++r) {
          const int row = rbase + r;
          if (row < M) {
            const float v = acc[mi][ni][r] * scale + bv;
            if (col < csplit)
              Kb3[((long long)zb * 496 + row) * 512 + col] = f32_bf16(v);
            else
              ATTo[((long long)zb * 496 + row) * 512 + (col - csplit)] = v;
          }
        }
      } else if constexpr (CTY == 9) {
        const float* ATTp = (const float*)Cp2;
        float* Of = (float*)Cp;
        #pragma unroll
        for (int r = 0; r < 4; ++r) {
          const int row = rbase + r;
          if (row < 496) {
            const float v = acc[mi][ni][r] * scale;
            const float a = ATTp[((long long)zb * 496 + row) * 512 + col];
            Of[((long long)zb * 3968 + (long long)csplit * 496 + row) * 512 + col] = v * a;
          } else if (row < M) {
            Kb3[(long long)zb * 524288 + (long long)(32 + row - 496) * 512 + col]
              = f32_bf16(acc[mi][ni][r] * scale);
          }
        }
      } else if (trside) {
        ushort4 v;
        v.x = f32_bf16(acc[mi][ni][0] * scale + bv);
        v.y = f32_bf16(acc[mi][ni][1] * scale + bv);
        v.z = f32_bf16(acc[mi][ni][2] * scale + bv);
        v.w = f32_bf16(acc[mi][ni][3] * scale + bv);
        *(ushort4*)(&Ch2[(long long)(rbase >> 10) * 524288
                         + (long long)(col - csplit) * 1024 + (rbase & 1023)]) = v;
      } else {
        #pragma unroll
        for (int r = 0; r < 4; ++r) {
          const int row = rbase + r;
          if (!GUARD || row < M) {
            const float v = acc[mi][ni][r] * scale + bv;
            if constexpr (CTY == 0)      Cf [(long long)row * Crs + col] = v;
            else                         Chn[(long long)row * Crs + col] = f32_bf16(v);
          }
        }
      }
    }
  }
}

// ---------------------------------------------------------------------------
// Flash MHA, QBLK=128 / 8 waves / 512 threads. Grid 256: f -> xcd=f&7, j=f>>3,
// bh=xcd+8*(j>>3), qt=j&7 (8 q-tiles of 128 per bh; 4 bh per XCD).
// Each K/V staging pass (8 kt of 128 keys) serves 128 q rows. Per-wave inner
// math identical to R7/R15 (16 q rows per wave, swapped-operand scalar softmax).
// LDS 70656 B (2 blocks/CU eligible). Ks reused as Os[128][72] for the O-transpose.
// ---------------------------------------------------------------------------
__global__ __launch_bounds__(512) void flash_mha(
    const unsigned short* __restrict__ QK, const unsigned short* __restrict__ Vt,
    unsigned short* __restrict__ OH)
{
  __shared__ unsigned short Ks[128][72];    // [key][d] 18.4KB (reused as Os[128][72])
  __shared__ unsigned short Vs[64][136];    // [d][key] 17.4KB
  __shared__ unsigned short Ps[128][136];   // [q][key] 34.8KB, per-wave 16-row slabs

  const int tid = threadIdx.x, lane = tid & 63, w = tid >> 6;   // w 0..7
  const int f = blockIdx.x;                 // 256 blocks
  const int xcd = f & 7, j = f >> 3;        // j 0..31
  const int bh = xcd + 8 * (j >> 3);        // 0..31, 4 bh per XCD
  const int qt = j & 7;                     // 0..7
  const int b = bh >> 3, h = bh & 7;
  const int q0 = qt * 128;
  const unsigned short* Qp = QK + (long long)b * 1048576 + h * 64;
  const unsigned short* Kp = Qp + 512;
  const unsigned short* Vp = Vt + (long long)b * 524288 + (long long)(h * 64) * 1024;
  unsigned short* Op = OH + (long long)b * 524288 + h * 64;

  const int lr = lane & 15, g = lane >> 4, lk = g * 8;
  const int wq = w * 16;                    // 0..112

  short8 qb[2];
  qb[0] = *(const short8*)(Qp + (long long)(q0 + wq + lr) * 1024 + lk);
  qb[1] = *(const short8*)(Qp + (long long)(q0 + wq + lr) * 1024 + 32 + lk);

  // staging with 512 threads: K 128x64 (4 thr/row, 2 uint4), V 64x128 (8 thr/row, 2 uint4)
  const int krow = tid >> 2, kcol = (tid & 3) * 16;
  const int vrow = tid >> 3, vcol = (tid & 7) * 16;

  uint4 kl[2], vl[2];
  auto loadKV = [&](int kt) {
    kl[0] = *(const uint4*)(Kp + (long long)(kt * 128 + krow) * 1024 + kcol);
    kl[1] = *(const uint4*)(Kp + (long long)(kt * 128 + krow) * 1024 + kcol + 8);
    vl[0] = *(const uint4*)(Vp + (long long)vrow * 1024 + kt * 128 + vcol);
    vl[1] = *(const uint4*)(Vp + (long long)vrow * 1024 + kt * 128 + vcol + 8);
  };
  auto writeKV = [&]() {
    *(uint4*)(&Ks[krow][kcol])     = kl[0];
    *(uint4*)(&Ks[krow][kcol + 8]) = kl[1];
    *(uint4*)(&Vs[vrow][vcol])     = vl[0];
    *(uint4*)(&Vs[vrow][vcol + 8]) = vl[1];
  };

  loadKV(0); writeKV();
  __syncthreads();

  f32x4 acc[4] = {};                        // O^T: acc[nd][r] = O[d=16nd+4g+r][q=wq+lr]
  float m = -1e30f, l = 0.f;                // per-lane scalars (q = wq+lr)

  for (int kt = 0; kt < 8; ++kt) {
    const bool more = kt < 7;
    if (more) loadKV(kt + 1);               // prefetch next K/V tile into registers

    // ---- S = K·Q^T : s[ni][r] = score[k=16ni+4g+r][q=wq+lr] ----
    f32x4 s[8] = {};
    #pragma unroll
    for (int ks = 0; ks < 2; ++ks)
      #pragma unroll
      for (int ni = 0; ni < 8; ++ni) {
        const short8 ka = *(const short8*)(&Ks[ni * 16 + lr][ks * 32 + lk]);
        s[ni] = __builtin_amdgcn_mfma_f32_16x16x32_bf16(ka, qb[ks], s[ni], 0, 0, 0);
      }

    // ---- per-lane scalar online softmax ----
    float rm = -1e30f;
    #pragma unroll
    for (int ni = 0; ni < 8; ++ni)
      #pragma unroll
      for (int r = 0; r < 4; ++r) { s[ni][r] *= 0.125f; rm = fmaxf(rm, s[ni][r]); }
    rm = fmaxf(rm, __shfl_xor(rm, 16));
    rm = fmaxf(rm, __shfl_xor(rm, 32));

    const float mn = fmaxf(m, rm);
    const float al = __expf(m - mn);
    m = mn;
    float ls = 0.f;
    #pragma unroll
    for (int ni = 0; ni < 8; ++ni)
      #pragma unroll
      for (int r = 0; r < 4; ++r) { s[ni][r] = __expf(s[ni][r] - m); ls += s[ni][r]; }
    ls += __shfl_xor(ls, 16);
    ls += __shfl_xor(ls, 32);
    l = l * al + ls;
    #pragma unroll
    for (int nd = 0; nd < 4; ++nd)
      #pragma unroll
      for (int r = 0; r < 4; ++r) acc[nd][r] *= al;

    // ---- P -> per-wave LDS slab: Ps[q=wq+lr][k=16ni+4g+r] ----
    #pragma unroll
    for (int ni = 0; ni < 8; ++ni)
      #pragma unroll
      for (int r = 0; r < 4; ++r)
        Ps[wq + lr][ni * 16 + (g << 2) + r] = f32_bf16(s[ni][r]);

    // ---- O^T += V·P^T ----
    #pragma unroll
    for (int ks2 = 0; ks2 < 4; ++ks2) {
      const short8 pb = *(const short8*)(&Ps[wq + lr][ks2 * 32 + lk]);
      #pragma unroll
      for (int nd = 0; nd < 4; ++nd) {
        const short8 va = *(const short8*)(&Vs[nd * 16 + lr][ks2 * 32 + lk]);
        acc[nd] = __builtin_amdgcn_mfma_f32_16x16x32_bf16(va, pb, acc[nd], 0, 0, 0);
      }
    }

    __syncthreads();
    if (more) { writeKV(); __syncthreads(); }
  }

  // ---- O^T -> Os (aliased on Ks[128][72]) -> coalesced OH write ----
  unsigned short (*Os)[72] = (unsigned short (*)[72])&Ks[0][0];
  const float inv = 1.0f / l;
  #pragma unroll
  for (int nd = 0; nd < 4; ++nd)
    #pragma unroll
    for (int r = 0; r < 4; ++r)
      Os[wq + lr][nd * 16 + (g << 2) + r] = f32_bf16(acc[nd][r] * inv);
  __syncthreads();
  const int orow = tid >> 2, ocol = (tid & 3) * 16;   // 128 rows x 4 thr/row
  const uint4 u0 = *(const uint4*)(&Os[orow][ocol]);
  const uint4 u1 = *(const uint4*)(&Os[orow][ocol + 8]);
  *(uint4*)(Op + (long long)(q0 + orow) * 512 + ocol) = u0;
  *(uint4*)(Op + (long long)(q0 + orow) * 512 + ocol + 8) = u1;
}

// ---------------------------------------------------------------------------
struct TP7 { const float* s[7]; unsigned short* d[7]; };
__global__ __launch_bounds__(256) void transpose7(TP7 tp)
{
  __shared__ float tile[32][33];
  const float* in = tp.s[blockIdx.z];
  unsigned short* out = tp.d[blockIdx.z];
  const int c0 = blockIdx.x * 32, r0 = blockIdx.y * 32;
  const int xx = threadIdx.x & 31, ys = threadIdx.x >> 5;
  #pragma unroll
  for (int yy = ys; yy < 32; yy += 8)
    tile[yy][xx] = in[(long long)(r0 + yy) * 512 + c0 + xx];
  __syncthreads();
  #pragma unroll
  for (int yy = ys; yy < 32; yy += 8)
    out[(long long)(c0 + yy) * 512 + r0 + xx] = f32_bf16(tile[xx][yy]);
}

// ---------------------------------------------------------------------------
// Row softmax, row length 1024, one wave per row. f32 in -> bf16 out (obuf).
// ---------------------------------------------------------------------------
__global__ __launch_bounds__(256) void softmax_rows_bf(
    const float* __restrict__ buf, unsigned short* __restrict__ obuf,
    int rowsPerZ, long long zStride)
{
  const int gr   = blockIdx.x * 4 + (threadIdx.x >> 6);
  const int lane = threadIdx.x & 63;
  const int z = gr / rowsPerZ;
  const int i = gr - z * rowsPerZ;
  const float* pf = buf + (long long)z * zStride + (long long)i * 1024 + lane * 16;
  float v[16];
  #pragma unroll
  for (int j = 0; j < 4; ++j) {
    const float4 f = ((const float4*)pf)[j];
    v[4*j+0] = f.x; v[4*j+1] = f.y; v[4*j+2] = f.z; v[4*j+3] = f.w;
  }
  float mx = v[0];
  #pragma unroll
  for (int j = 1; j < 16; ++j) mx = fmaxf(mx, v[j]);
  #pragma unroll
  for (int d = 32; d; d >>= 1) mx = fmaxf(mx, __shfl_xor(mx, d));
  float s = 0.0f;
  #pragma unroll
  for (int j = 0; j < 16; ++j) { v[j] = __expf(v[j] - mx); s += v[j]; }
  #pragma unroll
  for (int d = 32; d; d >>= 1) s += __shfl_xor(s, d);
  const float inv = 1.0f / s;
  unsigned short* ph = obuf + (long long)z * zStride + (long long)i * 1024 + lane * 16;
  unsigned uu[8];
  #pragma unroll
  for (int j = 0; j < 8; ++j) uu[j] = pk(v[2*j] * inv, v[2*j+1] * inv);
  ((uint4*)ph)[0] = make_uint4(uu[0], uu[1], uu[2], uu[3]);
  ((uint4*)ph)[1] = make_uint4(uu[4], uu[5], uu[6], uu[7]);
}

// --------------------------- elementwise helpers ---------------------------
__global__ __launch_bounds__(256) void copy_pm8(const float* __restrict__ pm, unsigned short* __restrict__ comb8)
{
  const int ci = blockIdx.y;
  const int idx = blockIdx.x * 256 + threadIdx.x;   // 8192 per ci
  const int b = idx >> 11, e = idx & 2047;
  const int row = e >> 6, d8 = (e & 63) * 8;
  const float* s = pm + row * 512 + d8;
  const float4 f0 = *(const float4*)s;
  const float4 f1 = *(const float4*)(s + 4);
  uint4 u; u.x = pk(f0.x, f0.y); u.y = pk(f0.z, f0.w); u.z = pk(f1.x, f1.y); u.w = pk(f1.z, f1.w);
  *(uint4*)(comb8 + (long long)ci * 2097152 + (long long)b * 524288 + row * 512 + d8) = u;
}

__global__ __launch_bounds__(256) void copy_chunk8(const float* __restrict__ x, unsigned short* __restrict__ comb8)
{
  const int ci = blockIdx.y;
  const int idx = blockIdx.x * 256 + threadIdx.x;   // 126976 per ci
  const int b = idx / 31744, e = idx % 31744;
  const int row = e >> 6, d8 = (e & 63) * 8;
  const float* s = x + ((long long)b * 3968 + ci * 496 + row) * 512 + d8;
  const float4 f0 = *(const float4*)s;
  const float4 f1 = *(const float4*)(s + 4);
  uint4 u; u.x = pk(f0.x, f0.y); u.y = pk(f0.z, f0.w); u.z = pk(f1.x, f1.y); u.w = pk(f1.z, f1.w);
  *(uint4*)(comb8 + (long long)ci * 2097152 + (long long)b * 524288 + (528 + row) * 512 + d8) = u;
}

__global__ __launch_bounds__(256) void init_kv(const float* __restrict__ mkb, const float* __restrict__ mvb,
                                               float* __restrict__ master, unsigned short* __restrict__ Kb)
{
  const int idx = blockIdx.x * 256 + threadIdx.x;   // 1M : [4096 rows][256 col4]
  const int c4 = (idx & 255) * 4;
  const long long row = idx >> 8;
  const float4 v = *(const float4*)((c4 < 512) ? (mkb + c4) : (mvb + c4 - 512));
  *(float4*)(master + row * 1024 + c4) = v;
  if (c4 < 512) {
    ushort4 h; h.x = f32_bf16(v.x); h.y = f32_bf16(v.y); h.z = f32_bf16(v.z); h.w = f32_bf16(v.w);
    *(ushort4*)(Kb + row * 512 + c4) = h;
  }
}

__global__ __launch_bounds__(256) void init_vt(const float* __restrict__ mvb, unsigned short* __restrict__ VT)
{
  const int idx = blockIdx.x * 256 + threadIdx.x;   // 262144 : [4][512][128 k8]
  const int k8 = (idx & 127) * 8;
  const int d  = (idx >> 7) & 511;
  const int b  = idx >> 16;
  const unsigned short hv = f32_bf16(mvb[d]);
  const ushort4 h4 = make_ushort4(hv, hv, hv, hv);
  unsigned short* dst = VT + (long long)b * 524288 + (long long)d * 1024 + k8;
  *(ushort4*)dst = h4; *(ushort4*)(dst + 4) = h4;
}

__global__ __launch_bounds__(256) void fuse_bias(const float* __restrict__ bq, const float* __restrict__ mq,
                                                 const float* __restrict__ mqb, float* __restrict__ bqm)
{
  const int c = blockIdx.x * 256 + threadIdx.x;     // 512
  float s = mqb[c];
  for (int j = 0; j < 512; ++j) s += bq[j] * mq[j * 512 + c];
  bqm[c] = s;
}

__global__ __launch_bounds__(256) void fuse_bias2(const float* __restrict__ aob,
                                                  const float* __restrict__ mkw, const float* __restrict__ mkb,
                                                  const float* __restrict__ mvw, const float* __restrict__ mvb,
                                                  float* __restrict__ baokv)
{
  const int c = blockIdx.x * 256 + threadIdx.x;     // 1024
  const float* w  = (c < 512) ? mkw : mvw;
  const float* bb = (c < 512) ? mkb : mvb;
  const int cc = c & 511;
  float s = bb[cc];
  for (int j = 0; j < 512; ++j) s += aob[j] * w[j * 512 + cc];
  baokv[c] = s;
}

// ---------------------------------------------------------------------------
extern "C" void kernel_launch(void* const* d_in, const int* in_sizes, int n_in,
                              void* d_out, int out_size, void* d_ws, size_t ws_size,
                              hipStream_t stream)
{
  (void)in_sizes; (void)n_in; (void)out_size; (void)ws_size;
  const float* x   = (const float*)d_in[0];
  const float* pm  = (const float*)d_in[1];
  const float* Wq  = (const float*)d_in[2];
  const float* bq  = (const float*)d_in[3];
  const float* mkw = (const float*)d_in[4];
  const float* mkb = (const float*)d_in[5];
  const float* mvw = (const float*)d_in[6];
  const float* mvb = (const float*)d_in[7];
  const float* mqw = (const float*)d_in[8];
  const float* mqb = (const float*)d_in[9];
  const float* aqw = (const float*)d_in[10];
  const float* aqb = (const float*)d_in[11];
  const float* akw = (const float*)d_in[12];
  const float* akb = (const float*)d_in[13];
  const float* avw = (const float*)d_in[14];
  const float* avb = (const float*)d_in[15];
  const float* aow = (const float*)d_in[16];
  const float* aob = (const float*)d_in[17];
  float* out = (float*)d_out;

  char* wsp = (char*)d_ws;
  size_t off = 0;
  auto alloc = [&](size_t b) -> void* { void* p = wsp + off; off += (b + 255) & ~(size_t)255; return p; };

  unsigned short* WTmq  = (unsigned short*)alloc(524288);   // mq^T bf16 [512][512]
  unsigned short* WKV   = (unsigned short*)alloc(1048576);  // [mk;mv]^T [1024][512]
  unsigned short* WQKV  = (unsigned short*)alloc(1572864);  // [aq;ak;av]^T [1536][512]
  unsigned short* Wqm   = (unsigned short*)alloc(524288);   // (Wq@mq)^T bf16
  unsigned short* WaoKV = (unsigned short*)alloc(1048576);  // (Wao@[mk|mv])^T bf16 [1024][512]
  unsigned short* WQA   = (unsigned short*)alloc(1048576);  // [(Wao@mq)^T ; ao^T] [1024][512]
  float* bqkv  = (float*)alloc(6144);
  float* bqm   = (float*)alloc(2048);
  float* baokv = (float*)alloc(4096);
  float* bqa   = (float*)alloc(4096);                       // [baomq | aob]
  float*          master = (float*)alloc(16777216);        // f32 [4,1024,1024] EMA'd [K|V]
  unsigned short* Kb   = (unsigned short*)alloc(4194304);  // bf16 [4,1024,512]
  unsigned short* VT   = (unsigned short*)alloc(4194304);  // bf16 [4,512,1024] (retrieve V^T)
  unsigned short* VTm  = (unsigned short*)alloc(4194304);  // bf16 [4,512,1024] (MHA V^T)
  unsigned short* QP1  = (unsigned short*)alloc(16252928); // bf16 [4,3968,512]
  unsigned short* QP   = (unsigned short*)alloc(2031616);  // bf16 [4,496,512] (qp2)
  unsigned short* comb8= (unsigned short*)alloc(33554432); // bf16 [8][4,1024,512]
  unsigned short* QKb  = (unsigned short*)alloc(8388608);  // bf16 [4,1024,1024] (q|k)
  unsigned short* OH   = (unsigned short*)alloc(4194304);  // bf16 [4,1024,512]
  float*          ATT  = (float*)alloc(4063232);           // f32 [4,496,512]
  float*          SC   = (float*)alloc(16515072);          // f32 [4,992,1024]
  unsigned short* SCb  = (unsigned short*)alloc(8257536);  // bf16 [4,992,1024]

  const long long XBS = 2031616, BS = 524288, QBS = 253952;
  const long long SCB2 = 1015808;               // 992*1024
  const float sr = 0.044194173824159216f;       // 1/sqrt(512)

  // -------- prep (once per call) --------
  TP7 tp;
  tp.s[0] = mqw; tp.d[0] = WTmq;
  tp.s[1] = mkw; tp.d[1] = WKV;
  tp.s[2] = mvw; tp.d[2] = WKV + 262144;
  tp.s[3] = aqw; tp.d[3] = WQKV;
  tp.s[4] = akw; tp.d[4] = WQKV + 262144;
  tp.s[5] = avw; tp.d[5] = WQKV + 524288;
  tp.s[6] = aow; tp.d[6] = WQA + 262144;        // ao^T -> second half of WQA
  transpose7<<<dim3(16,16,7),256,0,stream>>>(tp);
  gemm2<64,64,1,0,2,false,false,false,0><<<dim3(8,8,1),256,0,stream>>>(
    WTmq, 0, 0, 512, Wq, 0, 0, 512, Wqm, 0, 0, 512,
    nullptr, 0, nullptr, nullptr, 0, nullptr, 1.0f, 512, 512, 1);
  gemm2<64,64,1,0,2,false,false,false,0><<<dim3(16,8,1),256,0,stream>>>(
    WKV, 0, 0, 512, aow, 0, 0, 512, WaoKV, 0, 0, 512,
    nullptr, 0, nullptr, nullptr, 0, nullptr, 1.0f, 1024, 512, 1);
  gemm2<64,64,1,0,2,false,false,false,0><<<dim3(8,8,1),256,0,stream>>>(
    WTmq, 0, 0, 512, aow, 0, 0, 512, WQA, 0, 0, 512,
    nullptr, 0, nullptr, nullptr, 0, nullptr, 1.0f, 512, 512, 1);
  fuse_bias<<<2,256,0,stream>>>(bq, mqw, mqb, bqm);
  fuse_bias<<<2,256,0,stream>>>(aob, mqw, mqb, bqa);
  fuse_bias2<<<4,256,0,stream>>>(aob, mkw, mkb, mvw, mvb, baokv);
  hipMemcpyAsync(bqa + 512, aob, 2048, hipMemcpyDeviceToDevice, stream);
  // qp1 for ALL chunks: QP1 = bf16(x @ Wqm + bqm), M = 15872
  gemm2<128,64,0,1,2,false,true,false,0><<<dim3(124,8,1),256,0,stream>>>(
    x, 0, 0, 512, Wqm, 0, 0, 512,
    QP1, 0, 0, 512, nullptr, 0, nullptr, nullptr, 0, bqm, 1.0f, 15872, 512, 1);
  hipMemcpyAsync(bqkv,       aqb, 2048, hipMemcpyDeviceToDevice, stream);
  hipMemcpyAsync(bqkv + 512, akb, 2048, hipMemcpyDeviceToDevice, stream);
  hipMemcpyAsync(bqkv +1024, avb, 2048, hipMemcpyDeviceToDevice, stream);
  init_kv<<<4096,256,0,stream>>>(mkb, mvb, master, Kb);
  init_vt<<<1024,256,0,stream>>>(mvb, VT);
  copy_pm8<<<dim3(32,8),256,0,stream>>>(pm, comb8);
  copy_chunk8<<<dim3(496,8),256,0,stream>>>(x, comb8);

  // -------- prologue: scores1[0] + softmax + hist[0] (initial KV state) --------
  gemm2<64,64,1,1,0,true,false,false,0><<<dim3(8,16,4),256,0,stream>>>(
    QP1, XBS, 0, 512, Kb, BS, 0, 512,
    SC, SCB2, 0, 1024, nullptr, 0, nullptr, nullptr, 0, nullptr, sr, 496, 512, 1);
  softmax_rows_bf<<<496,256,0,stream>>>(SC, SCb, 496, SCB2);
  gemm2<64,64,1,1,2,true,false,false,0><<<dim3(8,8,4),256,0,stream>>>(
    SCb, SCB2, 0, 1024, VT, BS, 0, 1024,
    comb8 + 32 * 512, BS, 0, 512, nullptr, 0, nullptr, nullptr, 0, nullptr, 1.0f, 496, 1024, 1);

  for (int ci = 0; ci < 8; ++ci) {
    unsigned short* comb = comb8 + (long long)ci * 2097152;
    const bool last = (ci == 7);
    const int Mm = last ? 496 : 992;

    // MHA qkv (XCD-swizzled flat grid 768 = 32 M-stripes x 24 N-blocks)
    gemm2<128,64,1,1,4,false,true,false,24><<<dim3(768,1,1),256,0,stream>>>(
      comb, 0, 0, 512, WQKV, 0, 0, 512,
      QKb, 0, 0, 1024, VTm, 1024, nullptr, nullptr, 0, bqkv, 1.0f, 4096, 512, 1);
    flash_mha<<<256,512,0,stream>>>(QKb, VTm, OH);

    // KV-EMA (XCD-swizzled flat grid 512 = 32 x 16): master = 0.9*master + 0.1*(OH@WaoKV+b)
    gemm2<128,64,1,1,5,false,true,false,16><<<dim3(512,1,1),256,0,stream>>>(
      OH, 0, 0, 512, WaoKV, 0, 0, 512,
      master, 0, 0, 1024, VT, 512, Kb, nullptr, 0, baokv, 1.0f, 4096, 512, 1);
    // qp2 + ATT merged: [QP | ATT] = OH[:,528:] @ [Wao@mq | Wao] + [baomq | aob]
    gemm2<64,64,1,1,8,true,true,false,0><<<dim3(8,16,4),256,0,stream>>>(
      OH + 528 * 512, BS, 0, 512, WQA, 0, 0, 512,
      nullptr, 0, 0, 512, ATT, 512, QP, nullptr, 0, bqa, 1.0f, 496, 512, 1);

    // merged scores: rows 0..495 = qp2[ci], rows 496..991 = qp1[ci+1]
    gemm2<64,64,1,1,0,true,false,true,0><<<dim3(last?8:16,16,4),256,0,stream>>>(
      QP, QBS, 0, 512, Kb, BS, 0, 512,
      SC, SCB2, 0, 1024, nullptr, 0, nullptr,
      QP1 + (long long)(ci + 1) * 253952, XBS, nullptr, sr, Mm, 512, 1);
    softmax_rows_bf<<<(last?496:992),256,0,stream>>>(SC, SCb, Mm, SCB2);
    // merged PV: rows<496 -> out[ci] (outmul with ATT); rows>=496 -> hist[ci+1]
    gemm2<64,64,1,1,9,true,false,false,0><<<dim3(last?8:16,8,4),256,0,stream>>>(
      SCb, SCB2, 0, 1024, VT, BS, 0, 1024,
      out, 0, 0, 512, ATT, ci, last ? nullptr : (comb8 + (long long)(ci + 1) * 2097152),
      nullptr, 0, nullptr, 1.0f, Mm, 1024, 1);
  }
}